// Round 6
// baseline (429.290 us; speedup 1.0000x reference)
//
#include <hip/hip_runtime.h>
#include <hip/hip_cooperative_groups.h>

namespace cg = cooperative_groups;

#define ALP 0.1f          // alpha
#define OMA 0.9f          // 1 - alpha
#define D 64
#define DV 16             // float4 / ushort4 chunks per row
#define SH 7              // 128 nodes per bucket
#define NODES_PER_B 128
#define NBMAX 1024
#define CAP 16            // ELL slots per node (deg>16 -> overflow fixup)
#define OVF_MAX 65536

// ---------- bf16 helpers ----------
__device__ __forceinline__ unsigned short f2b(float f) {      // RNE
    unsigned u = __float_as_uint(f);
    unsigned r = u + 0x7fffu + ((u >> 16) & 1u);
    return (unsigned short)(r >> 16);
}
__device__ __forceinline__ float b2f(unsigned short u) {
    return __uint_as_float(((unsigned)u) << 16);
}

// ---------- single cooperative kernel: zero | p1+msg | ELL+gather | ovf ----------
__global__ __launch_bounds__(256, 4) void vsgc_all(
        const float4* __restrict__ h4, const float4* __restrict__ ini4,
        const float* __restrict__ bef_A, const float* __restrict__ aft_A,
        const float* __restrict__ bef_X,
        const int4* __restrict__ src4, const int4* __restrict__ dst4,
        float4* __restrict__ out4, ushort4* __restrict__ msgb,
        int* __restrict__ gcnt, int* __restrict__ buckets,
        int2* __restrict__ ovf, int* __restrict__ ovfCnt,
        int N, int E, int NB, int BCAP, int n16, int nInt4) {
    __shared__ int smraw[3 * NBMAX];          // 12 KB, reused across phases
    cg::grid_group grid = cg::this_grid();
    int tid = threadIdx.x;
    int G = gridDim.x;

    // ---- phase 0: zero global counters ----
    if (blockIdx.x == 0) {
        for (int i = tid; i < NBMAX; i += 256) gcnt[i] = 0;
        if (tid == 0) *ovfCnt = 0;
    }
    grid.sync();

    // ---- phase 1a: p1 bucket scatter (packed 4B records src<<SH | local_dst) ----
    {
        int* cnt   = smraw;
        int* gbase = smraw + NBMAX;
        int* pos   = smraw + 2 * NBMAX;
        for (int base4 = blockIdx.x * 256; base4 < nInt4; base4 += G * 256) {
#pragma unroll
            for (int j = 0; j < NBMAX / 256; ++j) { cnt[tid + j * 256] = 0; pos[tid + j * 256] = 0; }
            __syncthreads();
            int i4 = base4 + tid;
            bool v = i4 < nInt4;
            int4 sv = make_int4(0, 0, 0, 0), dv = sv;
            if (v) { sv = src4[i4]; dv = dst4[i4]; }
            int e0 = i4 << 2;
            int ss[4] = {sv.x, sv.y, sv.z, sv.w};
            int dd[4] = {dv.x, dv.y, dv.z, dv.w};
            bool ok[4];
#pragma unroll
            for (int k = 0; k < 4; ++k) ok[k] = v && (e0 + k < E);
#pragma unroll
            for (int k = 0; k < 4; ++k) if (ok[k]) atomicAdd(&cnt[dd[k] >> SH], 1);
            __syncthreads();
            for (int bb = tid; bb < NB; bb += 256)
                if (cnt[bb] > 0) gbase[bb] = atomicAdd(&gcnt[bb], cnt[bb]);
            __syncthreads();
            int pp[4];
#pragma unroll
            for (int k = 0; k < 4; ++k)
                pp[k] = ok[k] ? (gbase[dd[k] >> SH] + atomicAdd(&pos[dd[k] >> SH], 1)) : 0;
#pragma unroll
            for (int k = 0; k < 4; ++k) {
                if (!ok[k]) continue;
                int b = dd[k] >> SH;
                int pkt = (ss[k] << SH) | (dd[k] & (NODES_PER_B - 1));
                if (pp[k] < BCAP) buckets[(size_t)b * BCAP + pp[k]] = pkt;
                else { int o = atomicAdd(ovfCnt, 1); if (o < OVF_MAX) ovf[o] = make_int2(ss[k], dd[k]); }
            }
            __syncthreads();
        }
    }
    // ---- phase 1b: msg convert msgb[i] = bf16(h[i] * aft_A[node]) ----
    {
        int stride = G * 256;
        for (int i = blockIdx.x * 256 + tid; i < n16; i += stride) {
            float w = aft_A[i >> 4];
            float4 vv = h4[i];
            msgb[i] = make_ushort4(f2b(vv.x * w), f2b(vv.y * w), f2b(vv.z * w), f2b(vv.w * w));
        }
    }
    grid.sync();

    // ---- phase 2: per-bucket LDS ELL build + R5 gather body ----
    {
        int* npos = smraw;                      // [128]
        int* ells = smraw + NODES_PER_B;        // [128*16]
        unsigned clampN = (unsigned)(N - 1);
        int lane = tid & 63;
        int wv = tid >> 6;        // wave 0..3
        int w = lane >> 4;        // group 0..3
        int q = lane & 15;
        for (int b = blockIdx.x; b < NB; b += G) {
            if (tid < NODES_PER_B) npos[tid] = 0;
            __syncthreads();
            int nb = min(gcnt[b], BCAP);
            const int4* bp4 = (const int4*)(buckets + (size_t)b * BCAP);
            int nIter = (nb + 3) >> 2;
            for (int i4 = tid; i4 < nIter; i4 += 256) {
                int4 r4 = bp4[i4];
                int base = i4 << 2;
                int pk[4] = {r4.x, r4.y, r4.z, r4.w};
#pragma unroll
                for (int k = 0; k < 4; ++k) {
                    if (base + k >= nb) break;
                    int pkt = pk[k];
                    int l = pkt & (NODES_PER_B - 1);
                    int s = (int)(((unsigned)pkt) >> SH);
                    int slot = atomicAdd(&npos[l], 1);
                    if (slot < CAP) ells[l * CAP + slot] = s;
                    else { int o = atomicAdd(ovfCnt, 1); if (o < OVF_MAX) ovf[o] = make_int2(s, (b << SH) + l); }
                }
            }
            __syncthreads();
            int node0 = b << SH;
            for (int pair = wv; pair < NODES_PER_B / 2; pair += 4) {
                int l0 = pair * 2;
                int g0 = node0 + l0;
                if (g0 >= N) break;
                int g1 = g0 + 1;
                bool has1 = g1 < N;
                int l1c = has1 ? (l0 + 1) : l0;
                int g1c = node0 + l1c;
                size_t r0 = (size_t)g0 * DV + q;
                size_t r1 = (size_t)g1c * DV + q;
                int ev0 = ells[l0 * CAP + q];
                int ev1 = ells[l1c * CAP + q];
                int n0 = min(npos[l0], CAP);
                int n1 = has1 ? min(npos[l1c], CAP) : 0;
                float4 hv0 = h4[r0];
                float4 hv1 = h4[r1];
                float4 iv0 = ini4[r0];
                float4 iv1 = ini4[r1];
                float cb0 = ALP * bef_A[g0];
                float bx0 = ALP * bef_X[g0];
                float cb1 = ALP * bef_A[g1c];
                float bx1 = ALP * bef_X[g1c];
                float4 a0 = make_float4(0.f, 0.f, 0.f, 0.f);
                float4 a1 = a0;
#pragma unroll
                for (int k = 0; k < 4; ++k) {
                    int idx = w + 4 * k;
                    int s0 = __shfl(ev0, idx);
                    int s1 = __shfl(ev1, idx);
                    unsigned su0 = min((unsigned)s0, clampN);
                    unsigned su1 = min((unsigned)s1, clampN);
                    float m0 = (idx < n0) ? 1.f : 0.f;
                    float m1 = (idx < n1) ? 1.f : 0.f;
                    ushort4 q0 = msgb[(size_t)su0 * DV + q];
                    ushort4 q1 = msgb[(size_t)su1 * DV + q];
                    a0.x += m0 * b2f(q0.x); a0.y += m0 * b2f(q0.y);
                    a0.z += m0 * b2f(q0.z); a0.w += m0 * b2f(q0.w);
                    a1.x += m1 * b2f(q1.x); a1.y += m1 * b2f(q1.y);
                    a1.z += m1 * b2f(q1.z); a1.w += m1 * b2f(q1.w);
                }
                a0.x += __shfl_xor(a0.x, 16); a0.y += __shfl_xor(a0.y, 16);
                a0.z += __shfl_xor(a0.z, 16); a0.w += __shfl_xor(a0.w, 16);
                a0.x += __shfl_xor(a0.x, 32); a0.y += __shfl_xor(a0.y, 32);
                a0.z += __shfl_xor(a0.z, 32); a0.w += __shfl_xor(a0.w, 32);
                a1.x += __shfl_xor(a1.x, 16); a1.y += __shfl_xor(a1.y, 16);
                a1.z += __shfl_xor(a1.z, 16); a1.w += __shfl_xor(a1.w, 16);
                a1.x += __shfl_xor(a1.x, 32); a1.y += __shfl_xor(a1.y, 32);
                a1.z += __shfl_xor(a1.z, 32); a1.w += __shfl_xor(a1.w, 32);
                if (w == 0) {
                    float4 o;
                    o.x = OMA * hv0.x + bx0 * iv0.x + cb0 * a0.x;
                    o.y = OMA * hv0.y + bx0 * iv0.y + cb0 * a0.y;
                    o.z = OMA * hv0.z + bx0 * iv0.z + cb0 * a0.z;
                    o.w = OMA * hv0.w + bx0 * iv0.w + cb0 * a0.w;
                    out4[r0] = o;
                } else if (w == 1 && has1) {
                    float4 o;
                    o.x = OMA * hv1.x + bx1 * iv1.x + cb1 * a1.x;
                    o.y = OMA * hv1.y + bx1 * iv1.y + cb1 * a1.y;
                    o.z = OMA * hv1.z + bx1 * iv1.z + cb1 * a1.z;
                    o.w = OMA * hv1.w + bx1 * iv1.w + cb1 * a1.w;
                    out4[r1] = o;
                }
            }
            __syncthreads();
        }
    }
    grid.sync();

    // ---- phase 3: overflow fixup (fp32 exact; usually zero entries) ----
    {
        int total = min(*ovfCnt, OVF_MAX);
        int stride = G * 256;
        for (int t = blockIdx.x * 256 + tid; t < total * 16; t += stride) {
            int e = t >> 4, qq = t & 15;
            int2 r = ovf[e];
            float c = ALP * aft_A[r.x] * bef_A[r.y];
            float4 hv = h4[(size_t)r.x * DV + qq];
            float* op = (float*)out4 + (size_t)r.y * D + (qq << 2);
            unsafeAtomicAdd(op + 0, c * hv.x);
            unsafeAtomicAdd(op + 1, c * hv.y);
            unsafeAtomicAdd(op + 2, c * hv.z);
            unsafeAtomicAdd(op + 3, c * hv.w);
        }
    }
}

// ---------- last-resort fallback (atomic path) ----------
__global__ void vsgc_init(const float4* __restrict__ h, const float4* __restrict__ ini_h,
                          const float* __restrict__ bef_X, float4* __restrict__ out, int n4) {
    int i = blockIdx.x * blockDim.x + threadIdx.x;
    if (i >= n4) return;
    int node = i >> 4;
    float bx = ALP * bef_X[node];
    float4 hv = h[i];
    float4 iv = ini_h[i];
    float4 o;
    o.x = OMA * hv.x + bx * iv.x;
    o.y = OMA * hv.y + bx * iv.y;
    o.z = OMA * hv.z + bx * iv.z;
    o.w = OMA * hv.w + bx * iv.w;
    out[i] = o;
}
__global__ void vsgc_edges_atomic(const float4* __restrict__ h,
                                  const float* __restrict__ aft_A,
                                  const float* __restrict__ bef_A,
                                  const int* __restrict__ src,
                                  const int* __restrict__ dst,
                                  float* __restrict__ out, int E) {
    int tid = blockIdx.x * blockDim.x + threadIdx.x;
    int e = tid >> 4;
    int q = tid & 15;
    if (e >= E) return;
    int s = src[e];
    int d = dst[e];
    float c = ALP * aft_A[s] * bef_A[d];
    float4 hv = h[(size_t)s * DV + q];
    float* op = out + (size_t)d * D + (q << 2);
    unsafeAtomicAdd(op + 0, c * hv.x);
    unsafeAtomicAdd(op + 1, c * hv.y);
    unsafeAtomicAdd(op + 2, c * hv.z);
    unsafeAtomicAdd(op + 3, c * hv.w);
}

extern "C" void kernel_launch(void* const* d_in, const int* in_sizes, int n_in,
                              void* d_out, int out_size, void* d_ws, size_t ws_size,
                              hipStream_t stream) {
    const float* h     = (const float*)d_in[0];
    const float* ini_h = (const float*)d_in[1];
    const float* bef_A = (const float*)d_in[2];
    const float* aft_A = (const float*)d_in[3];
    const float* bef_X = (const float*)d_in[4];
    const int*   src   = (const int*)d_in[5];
    const int*   dst   = (const int*)d_in[6];
    float* out = (float*)d_out;

    const int N = in_sizes[0] / D;      // 100000
    const int E = in_sizes[5];          // 800000
    const int t = 256;

    int NB = (N + NODES_PER_B - 1) >> SH;            // 782
    int perB = (NB > 0) ? E / NB : 0;                // ~1023
    int BCAP = ((perB + perB / 4 + 256) + 3) & ~3;   // int4-aligned headroom

    // ws layout (256B aligned regions):
    // gcnt[1024] | ovfCnt[64] | ovf int2[OVF_MAX] | buckets[NB*BCAP] | msgb ushort[N*64]
    size_t o_gcnt = 0;
    size_t o_ovfc = NBMAX * 4;
    size_t o_ovf  = ((o_ovfc + 64 * 4 + 255) / 256) * 256;
    size_t o_bkt  = ((o_ovf + (size_t)OVF_MAX * 8 + 255) / 256) * 256;
    size_t o_msg  = ((o_bkt + (size_t)NB * BCAP * 4 + 255) / 256) * 256;
    size_t need   = o_msg + (size_t)N * 128;

    // cooperative-launch capability + co-residency sizing (host-only queries)
    int dev = 0;
    (void)hipGetDevice(&dev);
    int coop = 0;
    (void)hipDeviceGetAttribute(&coop, hipDeviceAttributeCooperativeLaunch, dev);
    int numCU = 0;
    (void)hipDeviceGetAttribute(&numCU, hipDeviceAttributeMultiprocessorCount, dev);
    int maxBpCU = 0;
    (void)hipOccupancyMaxActiveBlocksPerMultiprocessor(&maxBpCU, vsgc_all, 256, 0);

    if (coop && numCU > 0 && maxBpCU > 0 &&
        NB <= NBMAX && N <= (1 << (31 - SH)) && ws_size >= need) {
        int*  gcnt  = (int*)((char*)d_ws + o_gcnt);
        int*  ovfC  = (int*)((char*)d_ws + o_ovfc);
        int2* ovf   = (int2*)((char*)d_ws + o_ovf);
        int*  bkt   = (int*)((char*)d_ws + o_bkt);
        ushort4* msgb = (ushort4*)((char*)d_ws + o_msg);

        long long cap = (long long)maxBpCU * numCU;
        int G = (int)((cap < NBMAX) ? cap : NBMAX);

        const float4* h4p   = (const float4*)h;
        const float4* ini4p = (const float4*)ini_h;
        const int4*   src4p = (const int4*)src;
        const int4*   dst4p = (const int4*)dst;
        float4*       out4p = (float4*)out;
        int Nv = N, Ev = E, NBv = NB, BCAPv = BCAP;
        int n16 = N * DV;
        int nInt4 = (E + 3) >> 2;
        const float* befAp = bef_A;
        const float* aftAp = aft_A;
        const float* befXp = bef_X;

        void* args[] = {
            (void*)&h4p, (void*)&ini4p, (void*)&befAp, (void*)&aftAp, (void*)&befXp,
            (void*)&src4p, (void*)&dst4p, (void*)&out4p, (void*)&msgb,
            (void*)&gcnt, (void*)&bkt, (void*)&ovf, (void*)&ovfC,
            (void*)&Nv, (void*)&Ev, (void*)&NBv, (void*)&BCAPv, (void*)&n16, (void*)&nInt4
        };
        (void)hipLaunchCooperativeKernel(vsgc_all, dim3(G), dim3(256), args, 0, stream);
    } else {
        int n4 = N * DV;
        vsgc_init<<<(n4 + t - 1) / t, t, 0, stream>>>(
            (const float4*)h, (const float4*)ini_h, bef_X, (float4*)out, n4);
        long long total = (long long)E * DV;
        vsgc_edges_atomic<<<(int)((total + t - 1) / t), t, 0, stream>>>(
            (const float4*)h, aft_A, bef_A, src, dst, out, E);
    }
}

// Round 7
// 160.031 us; speedup vs baseline: 2.6825x; 2.6825x over previous
//
#include <hip/hip_runtime.h>

#define ALP 0.1f          // alpha
#define OMA 0.9f          // 1 - alpha
#define D 64
#define DV 16             // float4 chunks per row
#define SH 7              // 128 nodes per bucket
#define NODES_PER_B 128
#define NBMAX 1024
#define CAP 16            // ELL slots per node
#define OVL_CAP 512       // in-block overflow list (deg>16 edges; ~1/bucket expected)
#define OVF_MAX 65536

// ---------- pass 1: bucket scatter, packed 4B records (src<<SH | local_dst) ----------
__global__ __launch_bounds__(256) void vsgc_p1(
        const int4* __restrict__ src4, const int4* __restrict__ dst4,
        int* __restrict__ gcnt, int* __restrict__ buckets,
        int2* __restrict__ ovf, int* __restrict__ ovfCnt,
        int E, int NB, int BCAP) {
    __shared__ int cnt[NBMAX], gbase[NBMAX], pos[NBMAX];
    int tid = threadIdx.x;
#pragma unroll
    for (int j = 0; j < NBMAX / 256; ++j) { cnt[tid + j * 256] = 0; pos[tid + j * 256] = 0; }
    __syncthreads();
    int nInt4 = (E + 3) >> 2;
    int i0 = blockIdx.x * 512 + tid;
    int i1 = i0 + 256;
    bool v0 = i0 < nInt4, v1 = i1 < nInt4;
    int4 s0 = make_int4(0,0,0,0), d0 = s0, s1 = s0, d1 = s0;
    if (v0) { s0 = src4[i0]; d0 = dst4[i0]; }
    if (v1) { s1 = src4[i1]; d1 = dst4[i1]; }
    int e0 = i0 << 2, e1 = i1 << 2;
    int ss[8] = {s0.x, s0.y, s0.z, s0.w, s1.x, s1.y, s1.z, s1.w};
    int dd[8] = {d0.x, d0.y, d0.z, d0.w, d1.x, d1.y, d1.z, d1.w};
    bool ok[8];
#pragma unroll
    for (int k = 0; k < 4; ++k) { ok[k] = v0 && (e0 + k < E); ok[4 + k] = v1 && (e1 + k < E); }
#pragma unroll
    for (int k = 0; k < 8; ++k) if (ok[k]) atomicAdd(&cnt[dd[k] >> SH], 1);
    __syncthreads();
    for (int bb = tid; bb < NB; bb += 256)
        if (cnt[bb] > 0) gbase[bb] = atomicAdd(&gcnt[bb], cnt[bb]);
    __syncthreads();
    int pp[8];
#pragma unroll
    for (int k = 0; k < 8; ++k)
        pp[k] = ok[k] ? (gbase[dd[k] >> SH] + atomicAdd(&pos[dd[k] >> SH], 1)) : 0;
#pragma unroll
    for (int k = 0; k < 8; ++k) {
        if (!ok[k]) continue;
        int b = dd[k] >> SH;
        int pkt = (ss[k] << SH) | (dd[k] & (NODES_PER_B - 1));
        if (pp[k] < BCAP) buckets[(size_t)b * BCAP + pp[k]] = pkt;
        else { int o = atomicAdd(ovfCnt, 1); if (o < OVF_MAX) ovf[o] = make_int2(ss[k], dd[k]); }
    }
}

// ---------- pass 2: LDS ELL build + fp32 direct gather + in-block overflow ----------
__global__ __launch_bounds__(512) void p2_gather(
        const int* __restrict__ buckets, const int* __restrict__ gcnt,
        const float4* __restrict__ h4, const float4* __restrict__ ini4,
        const float* __restrict__ bef_A, const float* __restrict__ aft_A,
        const float* __restrict__ bef_X,
        const int2* __restrict__ ovf, const int* __restrict__ ovfCnt,
        float4* __restrict__ out4, int N, int BCAP) {
    __shared__ int npos[NODES_PER_B];
    __shared__ int ells[NODES_PER_B * CAP];    // 8 KB
    __shared__ int ovl[OVL_CAP];               // 2 KB
    __shared__ int novl;
    int b = blockIdx.x, tid = threadIdx.x;
    if (tid < NODES_PER_B) npos[tid] = 0;
    if (tid == 0) novl = 0;
    __syncthreads();
    // ---- phase A: records -> ELL (slot<CAP) or LDS overflow list ----
    int nb = min(gcnt[b], BCAP);
    const int4* bp4 = (const int4*)(buckets + (size_t)b * BCAP);
    const int*  bp  = buckets + (size_t)b * BCAP;
    int nIter = (nb + 3) >> 2;
    for (int i4 = tid; i4 < nIter; i4 += 512) {
        int4 r4 = bp4[i4];
        int base = i4 << 2;
        int pk[4] = {r4.x, r4.y, r4.z, r4.w};
#pragma unroll
        for (int k = 0; k < 4; ++k) {
            if (base + k >= nb) break;
            int pkt = pk[k];
            int l = pkt & (NODES_PER_B - 1);
            int slot = atomicAdd(&npos[l], 1);
            if (slot < CAP) ells[l * CAP + slot] = (int)(((unsigned)pkt) >> SH);
            else { int o = atomicAdd(&novl, 1); if (o < OVL_CAP) ovl[o] = pkt; }
        }
    }
    // consume p1's global bucket-overflow list (normally empty; one load)
    int gtot = min(*ovfCnt, OVF_MAX);
    for (int i = tid; i < gtot; i += 512) {
        int2 r = ovf[i];
        if ((r.y >> SH) == b) {
            int l = r.y & (NODES_PER_B - 1);
            int slot = atomicAdd(&npos[l], 1);
            if (slot < CAP) ells[l * CAP + slot] = r.x;
            else { int o = atomicAdd(&novl, 1); if (o < OVL_CAP) ovl[o] = (r.x << SH) | l; }
        }
    }
    __syncthreads();
    bool fast = (novl <= OVL_CAP);   // always true in practice
    // ---- phase B: gather, 2 nodes/wave, fp32 h rows scaled by aft_A ----
    int lane = tid & 63;
    int wv = tid >> 6;           // wave 0..7
    int w = lane >> 4;           // group 0..3
    int q = lane & 15;
    int node0 = b << SH;
    unsigned clampN = (unsigned)(N - 1);
    for (int pair = wv; pair < NODES_PER_B / 2; pair += 8) {
        int l0 = pair * 2;
        int g0 = node0 + l0;
        if (g0 >= N) break;
        int g1 = g0 + 1;
        bool has1 = g1 < N;
        int l1c = has1 ? (l0 + 1) : l0;
        int g1c = node0 + l1c;
        size_t r0 = (size_t)g0 * DV + q;
        size_t r1 = (size_t)g1c * DV + q;
        int ev0 = ells[l0 * CAP + q];
        int ev1 = ells[l1c * CAP + q];
        int n0 = fast ? min(npos[l0], CAP) : 0;
        int n1 = (fast && has1) ? min(npos[l1c], CAP) : 0;
        float4 hv0 = h4[r0];
        float4 hv1 = h4[r1];
        float4 iv0 = ini4[r0];
        float4 iv1 = ini4[r1];
        float cb0 = ALP * bef_A[g0];
        float bx0 = ALP * bef_X[g0];
        float cb1 = ALP * bef_A[g1c];
        float bx1 = ALP * bef_X[g1c];
        float4 a0 = make_float4(0.f, 0.f, 0.f, 0.f);
        float4 a1 = a0;
#pragma unroll
        for (int k = 0; k < 4; ++k) {
            int idx = w + 4 * k;
            int s0 = __shfl(ev0, idx);
            int s1 = __shfl(ev1, idx);
            unsigned su0 = min((unsigned)s0, clampN);   // clamp LDS garbage slots
            unsigned su1 = min((unsigned)s1, clampN);
            float c0 = (idx < n0) ? aft_A[su0] : 0.f;
            float c1 = (idx < n1) ? aft_A[su1] : 0.f;
            float4 m0 = h4[(size_t)su0 * DV + q];
            float4 m1 = h4[(size_t)su1 * DV + q];
            a0.x += c0 * m0.x; a0.y += c0 * m0.y;
            a0.z += c0 * m0.z; a0.w += c0 * m0.w;
            a1.x += c1 * m1.x; a1.y += c1 * m1.y;
            a1.z += c1 * m1.z; a1.w += c1 * m1.w;
        }
        a0.x += __shfl_xor(a0.x, 16); a0.y += __shfl_xor(a0.y, 16);
        a0.z += __shfl_xor(a0.z, 16); a0.w += __shfl_xor(a0.w, 16);
        a0.x += __shfl_xor(a0.x, 32); a0.y += __shfl_xor(a0.y, 32);
        a0.z += __shfl_xor(a0.z, 32); a0.w += __shfl_xor(a0.w, 32);
        a1.x += __shfl_xor(a1.x, 16); a1.y += __shfl_xor(a1.y, 16);
        a1.z += __shfl_xor(a1.z, 16); a1.w += __shfl_xor(a1.w, 16);
        a1.x += __shfl_xor(a1.x, 32); a1.y += __shfl_xor(a1.y, 32);
        a1.z += __shfl_xor(a1.z, 32); a1.w += __shfl_xor(a1.w, 32);
        if (w == 0) {
            float4 o;
            o.x = OMA * hv0.x + bx0 * iv0.x + cb0 * a0.x;
            o.y = OMA * hv0.y + bx0 * iv0.y + cb0 * a0.y;
            o.z = OMA * hv0.z + bx0 * iv0.z + cb0 * a0.z;
            o.w = OMA * hv0.w + bx0 * iv0.w + cb0 * a0.w;
            out4[r0] = o;
        } else if (w == 1 && has1) {
            float4 o;
            o.x = OMA * hv1.x + bx1 * iv1.x + cb1 * a1.x;
            o.y = OMA * hv1.y + bx1 * iv1.y + cb1 * a1.y;
            o.z = OMA * hv1.z + bx1 * iv1.z + cb1 * a1.z;
            o.w = OMA * hv1.w + bx1 * iv1.w + cb1 * a1.w;
            out4[r1] = o;
        }
    }
    __syncthreads();   // out[] for this bucket fully written before fixups
    // ---- phase C: overflow fixup, in-block (rare) ----
    if (fast) {
        int nov = novl;
        int g = tid >> 4, qq = tid & 15;
        for (int i = g; i < nov; i += 32) {
            int pkt = ovl[i];
            int l = pkt & (NODES_PER_B - 1);
            int s = (int)(((unsigned)pkt) >> SH);
            int node = node0 + l;
            float c = ALP * bef_A[node] * aft_A[s];
            float4 hm = h4[(size_t)s * DV + qq];
            float* op = (float*)out4 + (size_t)node * D + (qq << 2);
            unsafeAtomicAdd(op + 0, c * hm.x);
            unsafeAtomicAdd(op + 1, c * hm.y);
            unsafeAtomicAdd(op + 2, c * hm.z);
            unsafeAtomicAdd(op + 3, c * hm.w);
        }
    } else {
        // catastrophic-skew slow path (never taken at Poisson-8): phase B wrote
        // base terms only; add every record's contribution via atomics.
        for (int i = tid; i < nb; i += 512) {
            int pkt = bp[i];
            int l = pkt & (NODES_PER_B - 1);
            int s = (int)(((unsigned)pkt) >> SH);
            int node = node0 + l;
            float c = ALP * bef_A[node] * aft_A[s];
            const float4* hp = h4 + (size_t)s * DV;
            float* op = (float*)out4 + (size_t)node * D;
            for (int t = 0; t < DV; ++t) {
                float4 hm = hp[t];
                unsafeAtomicAdd(op + t * 4 + 0, c * hm.x);
                unsafeAtomicAdd(op + t * 4 + 1, c * hm.y);
                unsafeAtomicAdd(op + t * 4 + 2, c * hm.z);
                unsafeAtomicAdd(op + t * 4 + 3, c * hm.w);
            }
        }
        for (int i = tid; i < gtot; i += 512) {
            int2 r = ovf[i];
            if ((r.y >> SH) != b) continue;
            float c = ALP * bef_A[r.y] * aft_A[r.x];
            const float4* hp = h4 + (size_t)r.x * DV;
            float* op = (float*)out4 + (size_t)r.y * D;
            for (int t = 0; t < DV; ++t) {
                float4 hm = hp[t];
                unsafeAtomicAdd(op + t * 4 + 0, c * hm.x);
                unsafeAtomicAdd(op + t * 4 + 1, c * hm.y);
                unsafeAtomicAdd(op + t * 4 + 2, c * hm.z);
                unsafeAtomicAdd(op + t * 4 + 3, c * hm.w);
            }
        }
    }
}

// ---------- last-resort fallback (atomic path) ----------
__global__ void vsgc_init(const float4* __restrict__ h, const float4* __restrict__ ini_h,
                          const float* __restrict__ bef_X, float4* __restrict__ out, int n4) {
    int i = blockIdx.x * blockDim.x + threadIdx.x;
    if (i >= n4) return;
    int node = i >> 4;
    float bx = ALP * bef_X[node];
    float4 hv = h[i];
    float4 iv = ini_h[i];
    float4 o;
    o.x = OMA * hv.x + bx * iv.x;
    o.y = OMA * hv.y + bx * iv.y;
    o.z = OMA * hv.z + bx * iv.z;
    o.w = OMA * hv.w + bx * iv.w;
    out[i] = o;
}
__global__ void vsgc_edges_atomic(const float4* __restrict__ h,
                                  const float* __restrict__ aft_A,
                                  const float* __restrict__ bef_A,
                                  const int* __restrict__ src,
                                  const int* __restrict__ dst,
                                  float* __restrict__ out, int E) {
    int tid = blockIdx.x * blockDim.x + threadIdx.x;
    int e = tid >> 4;
    int q = tid & 15;
    if (e >= E) return;
    int s = src[e];
    int d = dst[e];
    float c = ALP * aft_A[s] * bef_A[d];
    float4 hv = h[(size_t)s * DV + q];
    float* op = out + (size_t)d * D + (q << 2);
    unsafeAtomicAdd(op + 0, c * hv.x);
    unsafeAtomicAdd(op + 1, c * hv.y);
    unsafeAtomicAdd(op + 2, c * hv.z);
    unsafeAtomicAdd(op + 3, c * hv.w);
}

extern "C" void kernel_launch(void* const* d_in, const int* in_sizes, int n_in,
                              void* d_out, int out_size, void* d_ws, size_t ws_size,
                              hipStream_t stream) {
    const float* h     = (const float*)d_in[0];
    const float* ini_h = (const float*)d_in[1];
    const float* bef_A = (const float*)d_in[2];
    const float* aft_A = (const float*)d_in[3];
    const float* bef_X = (const float*)d_in[4];
    const int*   src   = (const int*)d_in[5];
    const int*   dst   = (const int*)d_in[6];
    float* out = (float*)d_out;

    const int N = in_sizes[0] / D;      // 100000
    const int E = in_sizes[5];          // 800000
    const int t = 256;

    int NB = (N + NODES_PER_B - 1) >> SH;            // 782
    int perB = (NB > 0) ? E / NB : 0;                // ~1023
    int BCAP = ((perB + perB / 4 + 256) + 3) & ~3;   // int4-aligned headroom

    // ws layout (256B aligned): gcnt[1024] | ovfCnt[64] | ovf int2[OVF_MAX] | buckets[NB*BCAP]
    size_t o_gcnt = 0;
    size_t o_ovfc = NBMAX * 4;
    size_t o_ovf  = ((o_ovfc + 64 * 4 + 255) / 256) * 256;
    size_t o_bkt  = ((o_ovf + (size_t)OVF_MAX * 8 + 255) / 256) * 256;
    size_t need   = o_bkt + (size_t)NB * BCAP * 4;

    if (NB <= NBMAX && N <= (1 << (31 - SH)) && ws_size >= need) {
        int*  gcnt  = (int*)((char*)d_ws + o_gcnt);
        int*  ovfC  = (int*)((char*)d_ws + o_ovfc);
        int2* ovf   = (int2*)((char*)d_ws + o_ovf);
        int*  bkt   = (int*)((char*)d_ws + o_bkt);

        hipMemsetAsync(d_ws, 0, o_ovf, stream);   // gcnt + ovfCnt (tiny)

        int nInt4 = (E + 3) >> 2;
        int p1Blocks = (nInt4 + 511) / 512;
        vsgc_p1<<<p1Blocks, t, 0, stream>>>(
            (const int4*)src, (const int4*)dst, gcnt, bkt, ovf, ovfC, E, NB, BCAP);

        p2_gather<<<NB, 512, 0, stream>>>(
            bkt, gcnt, (const float4*)h, (const float4*)ini_h,
            bef_A, aft_A, bef_X, ovf, ovfC, (float4*)out, N, BCAP);
    } else {
        int n4 = N * DV;
        vsgc_init<<<(n4 + t - 1) / t, t, 0, stream>>>(
            (const float4*)h, (const float4*)ini_h, bef_X, (float4*)out, n4);
        long long total = (long long)E * DV;
        vsgc_edges_atomic<<<(int)((total + t - 1) / t), t, 0, stream>>>(
            (const float4*)h, aft_A, bef_A, src, dst, out, E);
    }
}

// Round 8
// 157.579 us; speedup vs baseline: 2.7243x; 1.0156x over previous
//
#include <hip/hip_runtime.h>

#define ALP 0.1f          // alpha
#define OMA 0.9f          // 1 - alpha
#define D 64
#define DV 16             // float4 chunks per row
#define SH 7              // 128 nodes per bucket
#define NODES_PER_B 128
#define NBMAX 1024
#define CAP 16            // ELL slots per node
#define OVL_CAP 512       // in-block overflow list (deg>16 edges; ~1/bucket expected)
#define OVF_MAX 65536

// ---------- pass 1: bucket scatter, packed 4B records (src<<SH | local_dst) ----------
// 512 threads, 1 int4 (4 edges) per thread: 12 waves/CU vs 6 in the 256-thread form.
__global__ __launch_bounds__(512) void vsgc_p1(
        const int4* __restrict__ src4, const int4* __restrict__ dst4,
        int* __restrict__ gcnt, int* __restrict__ buckets,
        int2* __restrict__ ovf, int* __restrict__ ovfCnt,
        int E, int NB, int BCAP) {
    __shared__ int cnt[NBMAX], gbase[NBMAX], pos[NBMAX];
    int tid = threadIdx.x;
    cnt[tid] = 0; cnt[tid + 512] = 0;
    pos[tid] = 0; pos[tid + 512] = 0;
    __syncthreads();
    int nInt4 = (E + 3) >> 2;
    int i4 = blockIdx.x * 512 + tid;
    bool v = i4 < nInt4;
    int4 sv = make_int4(0, 0, 0, 0), dv = sv;
    if (v) { sv = src4[i4]; dv = dst4[i4]; }
    int e0 = i4 << 2;
    int ss[4] = {sv.x, sv.y, sv.z, sv.w};
    int dd[4] = {dv.x, dv.y, dv.z, dv.w};
    bool ok[4];
#pragma unroll
    for (int k = 0; k < 4; ++k) ok[k] = v && (e0 + k < E);
#pragma unroll
    for (int k = 0; k < 4; ++k) if (ok[k]) atomicAdd(&cnt[dd[k] >> SH], 1);
    __syncthreads();
    for (int bb = tid; bb < NB; bb += 512)
        if (cnt[bb] > 0) gbase[bb] = atomicAdd(&gcnt[bb], cnt[bb]);
    __syncthreads();
    int pp[4];
#pragma unroll
    for (int k = 0; k < 4; ++k)
        pp[k] = ok[k] ? (gbase[dd[k] >> SH] + atomicAdd(&pos[dd[k] >> SH], 1)) : 0;
#pragma unroll
    for (int k = 0; k < 4; ++k) {
        if (!ok[k]) continue;
        int b = dd[k] >> SH;
        int pkt = (ss[k] << SH) | (dd[k] & (NODES_PER_B - 1));
        if (pp[k] < BCAP) buckets[(size_t)b * BCAP + pp[k]] = pkt;
        else { int o = atomicAdd(ovfCnt, 1); if (o < OVF_MAX) ovf[o] = make_int2(ss[k], dd[k]); }
    }
}

// ---------- pass 2: LDS ELL build + fp32 direct gather + in-block overflow ----------
__global__ __launch_bounds__(512) void p2_gather(
        const int* __restrict__ buckets, const int* __restrict__ gcnt,
        const float4* __restrict__ h4, const float4* __restrict__ ini4,
        const float* __restrict__ bef_A, const float* __restrict__ aft_A,
        const float* __restrict__ bef_X,
        const int2* __restrict__ ovf, const int* __restrict__ ovfCnt,
        float4* __restrict__ out4, int N, int BCAP) {
    __shared__ int npos[NODES_PER_B];
    __shared__ int ells[NODES_PER_B * CAP];    // 8 KB
    __shared__ int ovl[OVL_CAP];               // 2 KB
    __shared__ int novl;
    int b = blockIdx.x, tid = threadIdx.x;
    if (tid < NODES_PER_B) npos[tid] = 0;
    if (tid == 0) novl = 0;
    __syncthreads();
    // ---- phase A: records -> ELL (slot<CAP) or LDS overflow list ----
    int nb = min(gcnt[b], BCAP);
    const int4* bp4 = (const int4*)(buckets + (size_t)b * BCAP);
    const int*  bp  = buckets + (size_t)b * BCAP;
    int nIter = (nb + 3) >> 2;
    for (int i4 = tid; i4 < nIter; i4 += 512) {
        int4 r4 = bp4[i4];
        int base = i4 << 2;
        int pk[4] = {r4.x, r4.y, r4.z, r4.w};
#pragma unroll
        for (int k = 0; k < 4; ++k) {
            if (base + k >= nb) break;
            int pkt = pk[k];
            int l = pkt & (NODES_PER_B - 1);
            int slot = atomicAdd(&npos[l], 1);
            if (slot < CAP) ells[l * CAP + slot] = (int)(((unsigned)pkt) >> SH);
            else { int o = atomicAdd(&novl, 1); if (o < OVL_CAP) ovl[o] = pkt; }
        }
    }
    // consume p1's global bucket-overflow list (normally empty; one load)
    int gtot = min(*ovfCnt, OVF_MAX);
    for (int i = tid; i < gtot; i += 512) {
        int2 r = ovf[i];
        if ((r.y >> SH) == b) {
            int l = r.y & (NODES_PER_B - 1);
            int slot = atomicAdd(&npos[l], 1);
            if (slot < CAP) ells[l * CAP + slot] = r.x;
            else { int o = atomicAdd(&novl, 1); if (o < OVL_CAP) ovl[o] = (r.x << SH) | l; }
        }
    }
    __syncthreads();
    bool fast = (novl <= OVL_CAP);   // always true in practice
    // ---- phase B: gather, 2 nodes/wave, fp32 h rows scaled by aft_A ----
    int lane = tid & 63;
    int wv = tid >> 6;           // wave 0..7
    int w = lane >> 4;           // group 0..3
    int q = lane & 15;
    int node0 = b << SH;
    unsigned clampN = (unsigned)(N - 1);
    for (int pair = wv; pair < NODES_PER_B / 2; pair += 8) {
        int l0 = pair * 2;
        int g0 = node0 + l0;
        if (g0 >= N) break;
        int g1 = g0 + 1;
        bool has1 = g1 < N;
        int l1c = has1 ? (l0 + 1) : l0;
        int g1c = node0 + l1c;
        size_t r0 = (size_t)g0 * DV + q;
        size_t r1 = (size_t)g1c * DV + q;
        int ev0 = ells[l0 * CAP + q];
        int ev1 = ells[l1c * CAP + q];
        int n0 = fast ? min(npos[l0], CAP) : 0;
        int n1 = (fast && has1) ? min(npos[l1c], CAP) : 0;
        float4 hv0 = h4[r0];
        float4 hv1 = h4[r1];
        float4 iv0 = ini4[r0];
        float4 iv1 = ini4[r1];
        float cb0 = ALP * bef_A[g0];
        float bx0 = ALP * bef_X[g0];
        float cb1 = ALP * bef_A[g1c];
        float bx1 = ALP * bef_X[g1c];
        float4 a0 = make_float4(0.f, 0.f, 0.f, 0.f);
        float4 a1 = a0;
#pragma unroll
        for (int k = 0; k < 4; ++k) {
            int idx = w + 4 * k;
            int s0 = __shfl(ev0, idx);
            int s1 = __shfl(ev1, idx);
            unsigned su0 = min((unsigned)s0, clampN);   // clamp LDS garbage slots
            unsigned su1 = min((unsigned)s1, clampN);
            float c0 = (idx < n0) ? aft_A[su0] : 0.f;
            float c1 = (idx < n1) ? aft_A[su1] : 0.f;
            float4 m0 = h4[(size_t)su0 * DV + q];
            float4 m1 = h4[(size_t)su1 * DV + q];
            a0.x += c0 * m0.x; a0.y += c0 * m0.y;
            a0.z += c0 * m0.z; a0.w += c0 * m0.w;
            a1.x += c1 * m1.x; a1.y += c1 * m1.y;
            a1.z += c1 * m1.z; a1.w += c1 * m1.w;
        }
        a0.x += __shfl_xor(a0.x, 16); a0.y += __shfl_xor(a0.y, 16);
        a0.z += __shfl_xor(a0.z, 16); a0.w += __shfl_xor(a0.w, 16);
        a0.x += __shfl_xor(a0.x, 32); a0.y += __shfl_xor(a0.y, 32);
        a0.z += __shfl_xor(a0.z, 32); a0.w += __shfl_xor(a0.w, 32);
        a1.x += __shfl_xor(a1.x, 16); a1.y += __shfl_xor(a1.y, 16);
        a1.z += __shfl_xor(a1.z, 16); a1.w += __shfl_xor(a1.w, 16);
        a1.x += __shfl_xor(a1.x, 32); a1.y += __shfl_xor(a1.y, 32);
        a1.z += __shfl_xor(a1.z, 32); a1.w += __shfl_xor(a1.w, 32);
        if (w == 0) {
            float4 o;
            o.x = OMA * hv0.x + bx0 * iv0.x + cb0 * a0.x;
            o.y = OMA * hv0.y + bx0 * iv0.y + cb0 * a0.y;
            o.z = OMA * hv0.z + bx0 * iv0.z + cb0 * a0.z;
            o.w = OMA * hv0.w + bx0 * iv0.w + cb0 * a0.w;
            out4[r0] = o;
        } else if (w == 1 && has1) {
            float4 o;
            o.x = OMA * hv1.x + bx1 * iv1.x + cb1 * a1.x;
            o.y = OMA * hv1.y + bx1 * iv1.y + cb1 * a1.y;
            o.z = OMA * hv1.z + bx1 * iv1.z + cb1 * a1.z;
            o.w = OMA * hv1.w + bx1 * iv1.w + cb1 * a1.w;
            out4[r1] = o;
        }
    }
    __syncthreads();   // out[] for this bucket fully written before fixups
    // ---- phase C: overflow fixup, in-block (rare) ----
    if (fast) {
        int nov = novl;
        int g = tid >> 4, qq = tid & 15;
        for (int i = g; i < nov; i += 32) {
            int pkt = ovl[i];
            int l = pkt & (NODES_PER_B - 1);
            int s = (int)(((unsigned)pkt) >> SH);
            int node = node0 + l;
            float c = ALP * bef_A[node] * aft_A[s];
            float4 hm = h4[(size_t)s * DV + qq];
            float* op = (float*)out4 + (size_t)node * D + (qq << 2);
            unsafeAtomicAdd(op + 0, c * hm.x);
            unsafeAtomicAdd(op + 1, c * hm.y);
            unsafeAtomicAdd(op + 2, c * hm.z);
            unsafeAtomicAdd(op + 3, c * hm.w);
        }
    } else {
        // catastrophic-skew slow path (never taken at Poisson-8): phase B wrote
        // base terms only; add every record's contribution via atomics.
        for (int i = tid; i < nb; i += 512) {
            int pkt = bp[i];
            int l = pkt & (NODES_PER_B - 1);
            int s = (int)(((unsigned)pkt) >> SH);
            int node = node0 + l;
            float c = ALP * bef_A[node] * aft_A[s];
            const float4* hp = h4 + (size_t)s * DV;
            float* op = (float*)out4 + (size_t)node * D;
            for (int t = 0; t < DV; ++t) {
                float4 hm = hp[t];
                unsafeAtomicAdd(op + t * 4 + 0, c * hm.x);
                unsafeAtomicAdd(op + t * 4 + 1, c * hm.y);
                unsafeAtomicAdd(op + t * 4 + 2, c * hm.z);
                unsafeAtomicAdd(op + t * 4 + 3, c * hm.w);
            }
        }
        for (int i = tid; i < gtot; i += 512) {
            int2 r = ovf[i];
            if ((r.y >> SH) != b) continue;
            float c = ALP * bef_A[r.y] * aft_A[r.x];
            const float4* hp = h4 + (size_t)r.x * DV;
            float* op = (float*)out4 + (size_t)r.y * D;
            for (int t = 0; t < DV; ++t) {
                float4 hm = hp[t];
                unsafeAtomicAdd(op + t * 4 + 0, c * hm.x);
                unsafeAtomicAdd(op + t * 4 + 1, c * hm.y);
                unsafeAtomicAdd(op + t * 4 + 2, c * hm.z);
                unsafeAtomicAdd(op + t * 4 + 3, c * hm.w);
            }
        }
    }
}

// ---------- last-resort fallback (atomic path) ----------
__global__ void vsgc_init(const float4* __restrict__ h, const float4* __restrict__ ini_h,
                          const float* __restrict__ bef_X, float4* __restrict__ out, int n4) {
    int i = blockIdx.x * blockDim.x + threadIdx.x;
    if (i >= n4) return;
    int node = i >> 4;
    float bx = ALP * bef_X[node];
    float4 hv = h[i];
    float4 iv = ini_h[i];
    float4 o;
    o.x = OMA * hv.x + bx * iv.x;
    o.y = OMA * hv.y + bx * iv.y;
    o.z = OMA * hv.z + bx * iv.z;
    o.w = OMA * hv.w + bx * iv.w;
    out[i] = o;
}
__global__ void vsgc_edges_atomic(const float4* __restrict__ h,
                                  const float* __restrict__ aft_A,
                                  const float* __restrict__ bef_A,
                                  const int* __restrict__ src,
                                  const int* __restrict__ dst,
                                  float* __restrict__ out, int E) {
    int tid = blockIdx.x * blockDim.x + threadIdx.x;
    int e = tid >> 4;
    int q = tid & 15;
    if (e >= E) return;
    int s = src[e];
    int d = dst[e];
    float c = ALP * aft_A[s] * bef_A[d];
    float4 hv = h[(size_t)s * DV + q];
    float* op = out + (size_t)d * D + (q << 2);
    unsafeAtomicAdd(op + 0, c * hv.x);
    unsafeAtomicAdd(op + 1, c * hv.y);
    unsafeAtomicAdd(op + 2, c * hv.z);
    unsafeAtomicAdd(op + 3, c * hv.w);
}

extern "C" void kernel_launch(void* const* d_in, const int* in_sizes, int n_in,
                              void* d_out, int out_size, void* d_ws, size_t ws_size,
                              hipStream_t stream) {
    const float* h     = (const float*)d_in[0];
    const float* ini_h = (const float*)d_in[1];
    const float* bef_A = (const float*)d_in[2];
    const float* aft_A = (const float*)d_in[3];
    const float* bef_X = (const float*)d_in[4];
    const int*   src   = (const int*)d_in[5];
    const int*   dst   = (const int*)d_in[6];
    float* out = (float*)d_out;

    const int N = in_sizes[0] / D;      // 100000
    const int E = in_sizes[5];          // 800000
    const int t = 256;

    int NB = (N + NODES_PER_B - 1) >> SH;            // 782
    int perB = (NB > 0) ? E / NB : 0;                // ~1023
    int BCAP = ((perB + perB / 4 + 256) + 3) & ~3;   // int4-aligned headroom

    // ws layout (256B aligned): gcnt[1024] | ovfCnt[64] | ovf int2[OVF_MAX] | buckets[NB*BCAP]
    size_t o_gcnt = 0;
    size_t o_ovfc = NBMAX * 4;
    size_t o_ovf  = ((o_ovfc + 64 * 4 + 255) / 256) * 256;
    size_t o_bkt  = ((o_ovf + (size_t)OVF_MAX * 8 + 255) / 256) * 256;
    size_t need   = o_bkt + (size_t)NB * BCAP * 4;

    if (NB <= NBMAX && N <= (1 << (31 - SH)) && ws_size >= need) {
        int*  gcnt  = (int*)((char*)d_ws + o_gcnt);
        int*  ovfC  = (int*)((char*)d_ws + o_ovfc);
        int2* ovf   = (int2*)((char*)d_ws + o_ovf);
        int*  bkt   = (int*)((char*)d_ws + o_bkt);

        hipMemsetAsync(d_ws, 0, o_ovf, stream);   // gcnt + ovfCnt (tiny)

        int nInt4 = (E + 3) >> 2;
        int p1Blocks = (nInt4 + 511) / 512;
        vsgc_p1<<<p1Blocks, 512, 0, stream>>>(
            (const int4*)src, (const int4*)dst, gcnt, bkt, ovf, ovfC, E, NB, BCAP);

        p2_gather<<<NB, 512, 0, stream>>>(
            bkt, gcnt, (const float4*)h, (const float4*)ini_h,
            bef_A, aft_A, bef_X, ovf, ovfC, (float4*)out, N, BCAP);
    } else {
        int n4 = N * DV;
        vsgc_init<<<(n4 + t - 1) / t, t, 0, stream>>>(
            (const float4*)h, (const float4*)ini_h, bef_X, (float4*)out, n4);
        long long total = (long long)E * DV;
        vsgc_edges_atomic<<<(int)((total + t - 1) / t), t, 0, stream>>>(
            (const float4*)h, aft_A, bef_A, src, dst, out, E);
    }
}

// Round 9
// 156.243 us; speedup vs baseline: 2.7476x; 1.0086x over previous
//
#include <hip/hip_runtime.h>

#define ALP 0.1f          // alpha
#define OMA 0.9f          // 1 - alpha
#define D 64
#define DV 16             // float4 chunks per row
#define SH 6              // 64 nodes per bucket
#define NODES_PER_B 64
#define NBMAX 2048
#define CAP 16            // ELL slots per node
#define OVL_CAP 512       // in-block overflow list (deg>16 edges; <1/bucket expected)
#define OVF_MAX 65536

// ---------- pass 1: bucket scatter, packed 4B records (src<<SH | local_dst) ----------
__global__ __launch_bounds__(512) void vsgc_p1(
        const int4* __restrict__ src4, const int4* __restrict__ dst4,
        int* __restrict__ gcnt, int* __restrict__ buckets,
        int2* __restrict__ ovf, int* __restrict__ ovfCnt,
        int E, int NB, int BCAP) {
    __shared__ int cnt[NBMAX], gbase[NBMAX], pos[NBMAX];
    int tid = threadIdx.x;
#pragma unroll
    for (int j = 0; j < NBMAX / 512; ++j) { cnt[tid + j * 512] = 0; pos[tid + j * 512] = 0; }
    __syncthreads();
    int nInt4 = (E + 3) >> 2;
    int i4 = blockIdx.x * 512 + tid;
    bool v = i4 < nInt4;
    int4 sv = make_int4(0, 0, 0, 0), dv = sv;
    if (v) { sv = src4[i4]; dv = dst4[i4]; }
    int e0 = i4 << 2;
    int ss[4] = {sv.x, sv.y, sv.z, sv.w};
    int dd[4] = {dv.x, dv.y, dv.z, dv.w};
    bool ok[4];
#pragma unroll
    for (int k = 0; k < 4; ++k) ok[k] = v && (e0 + k < E);
#pragma unroll
    for (int k = 0; k < 4; ++k) if (ok[k]) atomicAdd(&cnt[dd[k] >> SH], 1);
    __syncthreads();
    for (int bb = tid; bb < NB; bb += 512)
        if (cnt[bb] > 0) gbase[bb] = atomicAdd(&gcnt[bb], cnt[bb]);
    __syncthreads();
    int pp[4];
#pragma unroll
    for (int k = 0; k < 4; ++k)
        pp[k] = ok[k] ? (gbase[dd[k] >> SH] + atomicAdd(&pos[dd[k] >> SH], 1)) : 0;
#pragma unroll
    for (int k = 0; k < 4; ++k) {
        if (!ok[k]) continue;
        int b = dd[k] >> SH;
        int pkt = (ss[k] << SH) | (dd[k] & (NODES_PER_B - 1));
        if (pp[k] < BCAP) buckets[(size_t)b * BCAP + pp[k]] = pkt;
        else { int o = atomicAdd(ovfCnt, 1); if (o < OVF_MAX) ovf[o] = make_int2(ss[k], dd[k]); }
    }
}

// ---------- pass 2: LDS ELL build + fp32 direct gather + in-block overflow ----------
// 64-node buckets, 256 threads (4 waves): 1563 blocks -> ~6 blocks/CU grid fill.
__global__ __launch_bounds__(256) void p2_gather(
        const int* __restrict__ buckets, const int* __restrict__ gcnt,
        const float4* __restrict__ h4, const float4* __restrict__ ini4,
        const float* __restrict__ bef_A, const float* __restrict__ aft_A,
        const float* __restrict__ bef_X,
        const int2* __restrict__ ovf, const int* __restrict__ ovfCnt,
        float4* __restrict__ out4, int N, int BCAP) {
    __shared__ int npos[NODES_PER_B];
    __shared__ int ells[NODES_PER_B * CAP];    // 4 KB
    __shared__ int ovl[OVL_CAP];               // 2 KB
    __shared__ int novl;
    int b = blockIdx.x, tid = threadIdx.x;
    if (tid < NODES_PER_B) npos[tid] = 0;
    if (tid == 0) novl = 0;
    __syncthreads();
    // ---- phase A: records -> ELL (slot<CAP) or LDS overflow list ----
    int nb = min(gcnt[b], BCAP);
    const int4* bp4 = (const int4*)(buckets + (size_t)b * BCAP);
    const int*  bp  = buckets + (size_t)b * BCAP;
    int nIter = (nb + 3) >> 2;
    for (int i4 = tid; i4 < nIter; i4 += 256) {
        int4 r4 = bp4[i4];
        int base = i4 << 2;
        int pk[4] = {r4.x, r4.y, r4.z, r4.w};
#pragma unroll
        for (int k = 0; k < 4; ++k) {
            if (base + k >= nb) break;
            int pkt = pk[k];
            int l = pkt & (NODES_PER_B - 1);
            int slot = atomicAdd(&npos[l], 1);
            if (slot < CAP) ells[l * CAP + slot] = (int)(((unsigned)pkt) >> SH);
            else { int o = atomicAdd(&novl, 1); if (o < OVL_CAP) ovl[o] = pkt; }
        }
    }
    // consume p1's global bucket-overflow list (normally empty; one scalar load)
    int gtot = min(*ovfCnt, OVF_MAX);
    for (int i = tid; i < gtot; i += 256) {
        int2 r = ovf[i];
        if ((r.y >> SH) == b) {
            int l = r.y & (NODES_PER_B - 1);
            int slot = atomicAdd(&npos[l], 1);
            if (slot < CAP) ells[l * CAP + slot] = r.x;
            else { int o = atomicAdd(&novl, 1); if (o < OVL_CAP) ovl[o] = (r.x << SH) | l; }
        }
    }
    __syncthreads();
    bool fast = (novl <= OVL_CAP);   // always true in practice
    // ---- phase B: gather, 2 nodes/wave, fp32 h rows scaled by aft_A ----
    int lane = tid & 63;
    int wv = tid >> 6;           // wave 0..3
    int w = lane >> 4;           // group 0..3
    int q = lane & 15;
    int node0 = b << SH;
    unsigned clampN = (unsigned)(N - 1);
    for (int pair = wv; pair < NODES_PER_B / 2; pair += 4) {
        int l0 = pair * 2;
        int g0 = node0 + l0;
        if (g0 >= N) break;
        int g1 = g0 + 1;
        bool has1 = g1 < N;
        int l1c = has1 ? (l0 + 1) : l0;
        int g1c = node0 + l1c;
        size_t r0 = (size_t)g0 * DV + q;
        size_t r1 = (size_t)g1c * DV + q;
        int ev0 = ells[l0 * CAP + q];
        int ev1 = ells[l1c * CAP + q];
        int n0 = fast ? min(npos[l0], CAP) : 0;
        int n1 = (fast && has1) ? min(npos[l1c], CAP) : 0;
        float4 hv0 = h4[r0];
        float4 hv1 = h4[r1];
        float4 iv0 = ini4[r0];
        float4 iv1 = ini4[r1];
        float cb0 = ALP * bef_A[g0];
        float bx0 = ALP * bef_X[g0];
        float cb1 = ALP * bef_A[g1c];
        float bx1 = ALP * bef_X[g1c];
        float4 a0 = make_float4(0.f, 0.f, 0.f, 0.f);
        float4 a1 = a0;
#pragma unroll
        for (int k = 0; k < 4; ++k) {
            int idx = w + 4 * k;
            int s0 = __shfl(ev0, idx);
            int s1 = __shfl(ev1, idx);
            unsigned su0 = min((unsigned)s0, clampN);   // clamp LDS garbage slots
            unsigned su1 = min((unsigned)s1, clampN);
            float c0 = (idx < n0) ? aft_A[su0] : 0.f;
            float c1 = (idx < n1) ? aft_A[su1] : 0.f;
            float4 m0 = h4[(size_t)su0 * DV + q];
            float4 m1 = h4[(size_t)su1 * DV + q];
            a0.x += c0 * m0.x; a0.y += c0 * m0.y;
            a0.z += c0 * m0.z; a0.w += c0 * m0.w;
            a1.x += c1 * m1.x; a1.y += c1 * m1.y;
            a1.z += c1 * m1.z; a1.w += c1 * m1.w;
        }
        a0.x += __shfl_xor(a0.x, 16); a0.y += __shfl_xor(a0.y, 16);
        a0.z += __shfl_xor(a0.z, 16); a0.w += __shfl_xor(a0.w, 16);
        a0.x += __shfl_xor(a0.x, 32); a0.y += __shfl_xor(a0.y, 32);
        a0.z += __shfl_xor(a0.z, 32); a0.w += __shfl_xor(a0.w, 32);
        a1.x += __shfl_xor(a1.x, 16); a1.y += __shfl_xor(a1.y, 16);
        a1.z += __shfl_xor(a1.z, 16); a1.w += __shfl_xor(a1.w, 16);
        a1.x += __shfl_xor(a1.x, 32); a1.y += __shfl_xor(a1.y, 32);
        a1.z += __shfl_xor(a1.z, 32); a1.w += __shfl_xor(a1.w, 32);
        if (w == 0) {
            float4 o;
            o.x = OMA * hv0.x + bx0 * iv0.x + cb0 * a0.x;
            o.y = OMA * hv0.y + bx0 * iv0.y + cb0 * a0.y;
            o.z = OMA * hv0.z + bx0 * iv0.z + cb0 * a0.z;
            o.w = OMA * hv0.w + bx0 * iv0.w + cb0 * a0.w;
            out4[r0] = o;
        } else if (w == 1 && has1) {
            float4 o;
            o.x = OMA * hv1.x + bx1 * iv1.x + cb1 * a1.x;
            o.y = OMA * hv1.y + bx1 * iv1.y + cb1 * a1.y;
            o.z = OMA * hv1.z + bx1 * iv1.z + cb1 * a1.z;
            o.w = OMA * hv1.w + bx1 * iv1.w + cb1 * a1.w;
            out4[r1] = o;
        }
    }
    __syncthreads();   // out[] for this bucket fully written before fixups
    // ---- phase C: overflow fixup, in-block (rare) ----
    if (fast) {
        int nov = novl;
        int g = tid >> 4, qq = tid & 15;
        for (int i = g; i < nov; i += 16) {
            int pkt = ovl[i];
            int l = pkt & (NODES_PER_B - 1);
            int s = (int)(((unsigned)pkt) >> SH);
            int node = node0 + l;
            float c = ALP * bef_A[node] * aft_A[s];
            float4 hm = h4[(size_t)s * DV + qq];
            float* op = (float*)out4 + (size_t)node * D + (qq << 2);
            unsafeAtomicAdd(op + 0, c * hm.x);
            unsafeAtomicAdd(op + 1, c * hm.y);
            unsafeAtomicAdd(op + 2, c * hm.z);
            unsafeAtomicAdd(op + 3, c * hm.w);
        }
    } else {
        // catastrophic-skew slow path (never taken at Poisson-8)
        for (int i = tid; i < nb; i += 256) {
            int pkt = bp[i];
            int l = pkt & (NODES_PER_B - 1);
            int s = (int)(((unsigned)pkt) >> SH);
            int node = node0 + l;
            float c = ALP * bef_A[node] * aft_A[s];
            const float4* hp = h4 + (size_t)s * DV;
            float* op = (float*)out4 + (size_t)node * D;
            for (int t = 0; t < DV; ++t) {
                float4 hm = hp[t];
                unsafeAtomicAdd(op + t * 4 + 0, c * hm.x);
                unsafeAtomicAdd(op + t * 4 + 1, c * hm.y);
                unsafeAtomicAdd(op + t * 4 + 2, c * hm.z);
                unsafeAtomicAdd(op + t * 4 + 3, c * hm.w);
            }
        }
        for (int i = tid; i < gtot; i += 256) {
            int2 r = ovf[i];
            if ((r.y >> SH) != b) continue;
            float c = ALP * bef_A[r.y] * aft_A[r.x];
            const float4* hp = h4 + (size_t)r.x * DV;
            float* op = (float*)out4 + (size_t)r.y * D;
            for (int t = 0; t < DV; ++t) {
                float4 hm = hp[t];
                unsafeAtomicAdd(op + t * 4 + 0, c * hm.x);
                unsafeAtomicAdd(op + t * 4 + 1, c * hm.y);
                unsafeAtomicAdd(op + t * 4 + 2, c * hm.z);
                unsafeAtomicAdd(op + t * 4 + 3, c * hm.w);
            }
        }
    }
}

// ---------- last-resort fallback (atomic path) ----------
__global__ void vsgc_init(const float4* __restrict__ h, const float4* __restrict__ ini_h,
                          const float* __restrict__ bef_X, float4* __restrict__ out, int n4) {
    int i = blockIdx.x * blockDim.x + threadIdx.x;
    if (i >= n4) return;
    int node = i >> 4;
    float bx = ALP * bef_X[node];
    float4 hv = h[i];
    float4 iv = ini_h[i];
    float4 o;
    o.x = OMA * hv.x + bx * iv.x;
    o.y = OMA * hv.y + bx * iv.y;
    o.z = OMA * hv.z + bx * iv.z;
    o.w = OMA * hv.w + bx * iv.w;
    out[i] = o;
}
__global__ void vsgc_edges_atomic(const float4* __restrict__ h,
                                  const float* __restrict__ aft_A,
                                  const float* __restrict__ bef_A,
                                  const int* __restrict__ src,
                                  const int* __restrict__ dst,
                                  float* __restrict__ out, int E) {
    int tid = blockIdx.x * blockDim.x + threadIdx.x;
    int e = tid >> 4;
    int q = tid & 15;
    if (e >= E) return;
    int s = src[e];
    int d = dst[e];
    float c = ALP * aft_A[s] * bef_A[d];
    float4 hv = h[(size_t)s * DV + q];
    float* op = out + (size_t)d * D + (q << 2);
    unsafeAtomicAdd(op + 0, c * hv.x);
    unsafeAtomicAdd(op + 1, c * hv.y);
    unsafeAtomicAdd(op + 2, c * hv.z);
    unsafeAtomicAdd(op + 3, c * hv.w);
}

extern "C" void kernel_launch(void* const* d_in, const int* in_sizes, int n_in,
                              void* d_out, int out_size, void* d_ws, size_t ws_size,
                              hipStream_t stream) {
    const float* h     = (const float*)d_in[0];
    const float* ini_h = (const float*)d_in[1];
    const float* bef_A = (const float*)d_in[2];
    const float* aft_A = (const float*)d_in[3];
    const float* bef_X = (const float*)d_in[4];
    const int*   src   = (const int*)d_in[5];
    const int*   dst   = (const int*)d_in[6];
    float* out = (float*)d_out;

    const int N = in_sizes[0] / D;      // 100000
    const int E = in_sizes[5];          // 800000
    const int t = 256;

    int NB = (N + NODES_PER_B - 1) >> SH;            // 1563
    int perB = (NB > 0) ? E / NB : 0;                // ~511
    int BCAP = ((perB + perB / 4 + 256) + 3) & ~3;   // int4-aligned headroom

    // ws layout (256B aligned): gcnt[2048] | ovfCnt[64] | ovf int2[OVF_MAX] | buckets[NB*BCAP]
    size_t o_gcnt = 0;
    size_t o_ovfc = NBMAX * 4;
    size_t o_ovf  = ((o_ovfc + 64 * 4 + 255) / 256) * 256;
    size_t o_bkt  = ((o_ovf + (size_t)OVF_MAX * 8 + 255) / 256) * 256;
    size_t need   = o_bkt + (size_t)NB * BCAP * 4;

    if (NB <= NBMAX && N <= (1 << (31 - SH)) && ws_size >= need) {
        int*  gcnt  = (int*)((char*)d_ws + o_gcnt);
        int*  ovfC  = (int*)((char*)d_ws + o_ovfc);
        int2* ovf   = (int2*)((char*)d_ws + o_ovf);
        int*  bkt   = (int*)((char*)d_ws + o_bkt);

        hipMemsetAsync(d_ws, 0, o_ovf, stream);   // gcnt + ovfCnt (tiny)

        int nInt4 = (E + 3) >> 2;
        int p1Blocks = (nInt4 + 511) / 512;
        vsgc_p1<<<p1Blocks, 512, 0, stream>>>(
            (const int4*)src, (const int4*)dst, gcnt, bkt, ovf, ovfC, E, NB, BCAP);

        p2_gather<<<NB, 256, 0, stream>>>(
            bkt, gcnt, (const float4*)h, (const float4*)ini_h,
            bef_A, aft_A, bef_X, ovf, ovfC, (float4*)out, N, BCAP);
    } else {
        int n4 = N * DV;
        vsgc_init<<<(n4 + t - 1) / t, t, 0, stream>>>(
            (const float4*)h, (const float4*)ini_h, bef_X, (float4*)out, n4);
        long long total = (long long)E * DV;
        vsgc_edges_atomic<<<(int)((total + t - 1) / t), t, 0, stream>>>(
            (const float4*)h, aft_A, bef_A, src, dst, out, E);
    }
}